// Round 5
// baseline (503.138 us; speedup 1.0000x reference)
//
#include <hip/hip_runtime.h>
#include <math.h>

#define N_NODES 50000
#define E_EDGES 600000
#define D_DIM 128
#define OUT_DIM 40
#define N_ITERS 5
#define GAMMA_C 0.1f
#define EPS_C 0.1f
#define SCAN_BLOCKS 196          // 196*256 = 50176 >= N_NODES

typedef short v8s __attribute__((ext_vector_type(8)));   // 8 bf16 (4 VGPRs)
typedef float v4f __attribute__((ext_vector_type(4)));   // MFMA accumulator
typedef unsigned int uint;
typedef unsigned short ushort;

__device__ __forceinline__ ushort f2bf(float f) {        // RNE fp32->bf16
    union { float f; uint u; } v; v.f = f;
    uint u = v.u;
    uint r = 0x7fffu + ((u >> 16) & 1u);
    return (ushort)((u + r) >> 16);
}
__device__ __forceinline__ float bf2f(ushort h) {
    union { uint u; float f; } v; v.u = ((uint)h) << 16;
    return v.f;
}

// ---------------------------------------------------------------------------
// Weight prep (once): WembH = bf16(W_emb);
// Wcat2[c][k] (row-stride 256): k<128 -> A[c][k] = Wanti[c][k]-Wanti[k][c]-g*I,
//                               k>=128 -> W_lin[c][k-128]
// Fused conv GEMM computes [xh | aggxh] @ Wcat2^T  (K=256).
// ---------------------------------------------------------------------------
__global__ __launch_bounds__(256) void prep_w_kernel(const float* __restrict__ Wemb,
                                                     const float* __restrict__ Wlin,
                                                     const float* __restrict__ Wanti,
                                                     ushort* __restrict__ WembH,
                                                     ushort* __restrict__ Wcat2H) {
    int i = blockIdx.x * 256 + threadIdx.x;              // 16384
    int r = i >> 7, c = i & 127;
    WembH[i] = f2bf(Wemb[i]);
    float a = Wanti[r * 128 + c] - Wanti[c * 128 + r];
    if (r == c) a -= GAMMA_C;
    Wcat2H[r * 256 + c]       = f2bf(a);
    Wcat2H[r * 256 + 128 + c] = f2bf(Wlin[r * 128 + c]);
}

// ---------------------------------------------------------------------------
// embed GEMM: x = x0 @ W_emb^T + b_emb  (fp32 in, writes fp32 x AND bf16 xh)
// Tile 128x128, 4 waves, K=128 staged, XOR-swizzled conflict-free LDS.
// Fragment layouts (verified m89/m120): A[m=lane&15][k=quad*8+j],
// B[n=lane&15][k=quad*8+j], C/D: col=lane&15, row=quad*4+reg.
// ---------------------------------------------------------------------------
__global__ __launch_bounds__(256) void mfma_embed_gemm(const float* __restrict__ Xf,
                                                       const ushort* __restrict__ Wh,
                                                       const float* __restrict__ bias,
                                                       float* __restrict__ xF,
                                                       ushort* __restrict__ xH,
                                                       int M) {
    __shared__ ushort Xs[128 * 128];
    __shared__ ushort Ws[128 * 128];
    const int tid = threadIdx.x;
    const int rowBase = blockIdx.x * 128;

#pragma unroll
    for (int p = 0; p < 8; ++p) {
        int cid = p * 256 + tid;
        int r = cid >> 4, c8 = cid & 15;
        int gr = rowBase + r;
        uint4 val = make_uint4(0, 0, 0, 0);
        if (gr < M) {
            const float* ptr = Xf + (size_t)gr * 128 + c8 * 8;
            float4 f0 = *(const float4*)ptr;
            float4 f1 = *(const float4*)(ptr + 4);
            val.x = (uint)f2bf(f0.x) | ((uint)f2bf(f0.y) << 16);
            val.y = (uint)f2bf(f0.z) | ((uint)f2bf(f0.w) << 16);
            val.z = (uint)f2bf(f1.x) | ((uint)f2bf(f1.y) << 16);
            val.w = (uint)f2bf(f1.z) | ((uint)f2bf(f1.w) << 16);
        }
        *(uint4*)(Xs + r * 128 + ((c8 ^ (r & 7)) << 3)) = val;
        uint4 wv = *(const uint4*)(Wh + (size_t)r * 128 + c8 * 8);
        *(uint4*)(Ws + r * 128 + ((c8 ^ (r & 7)) << 3)) = wv;
    }
    __syncthreads();

    const int lane = tid & 63;
    const int wv = tid >> 6;
    const int wrow = (wv & 1) * 64;
    const int wcol = (wv >> 1) * 64;
    const int l16 = lane & 15;
    const int q = lane >> 4;

    v4f acc[4][4];
#pragma unroll
    for (int i = 0; i < 4; ++i)
#pragma unroll
        for (int j = 0; j < 4; ++j) {
            v4f z = {0.f, 0.f, 0.f, 0.f};
            acc[i][j] = z;
        }

#pragma unroll
    for (int ks = 0; ks < 4; ++ks) {
        const int chunk = ks * 4 + q;
        v8s a[4], b[4];
#pragma unroll
        for (int i = 0; i < 4; ++i) {
            int m = wrow + i * 16 + l16;
            a[i] = *(const v8s*)(Xs + m * 128 + ((chunk ^ (m & 7)) << 3));
        }
#pragma unroll
        for (int j = 0; j < 4; ++j) {
            int n = wcol + j * 16 + l16;
            b[j] = *(const v8s*)(Ws + n * 128 + ((chunk ^ (n & 7)) << 3));
        }
#pragma unroll
        for (int i = 0; i < 4; ++i)
#pragma unroll
            for (int j = 0; j < 4; ++j)
                acc[i][j] = __builtin_amdgcn_mfma_f32_16x16x32_bf16(a[i], b[j], acc[i][j], 0, 0, 0);
    }

#pragma unroll
    for (int j = 0; j < 4; ++j) {
        int col = wcol + j * 16 + l16;
        float bj = bias[col];
#pragma unroll
        for (int i = 0; i < 4; ++i) {
            int grB = rowBase + wrow + i * 16 + q * 4;
#pragma unroll
            for (int r = 0; r < 4; ++r) {
                int gr = grB + r;
                if (gr < M) {
                    float v = acc[i][j][r] + bj;
                    xF[(size_t)gr * 128 + col] = v;
                    xH[(size_t)gr * 128 + col] = f2bf(v);
                }
            }
        }
    }
}

// ---------------------------------------------------------------------------
// Fused conv GEMM + update (per iteration):
//   conv = [xh | aggxh] @ Wcat2^T + b_conv     (K=256, two staged K=128 chunks)
//   x += eps*tanh(conv); xh = bf16(x)          (fused epilogue)
// Each block's X rows == the rows it overwrites -> no cross-block hazard.
// ---------------------------------------------------------------------------
__global__ __launch_bounds__(256) void mfma_conv_update(
        const ushort* __restrict__ xh, const ushort* __restrict__ aggxh,
        const ushort* __restrict__ Wcat2, const float* __restrict__ bconv,
        float* __restrict__ xF, ushort* __restrict__ xhOut, int M) {
    __shared__ ushort Xs[128 * 128];
    __shared__ ushort Ws[128 * 128];
    const int tid = threadIdx.x;
    const int rowBase = blockIdx.x * 128;

    const int lane = tid & 63;
    const int wv = tid >> 6;
    const int wrow = (wv & 1) * 64;
    const int wcol = (wv >> 1) * 64;
    const int l16 = lane & 15;
    const int q = lane >> 4;

    v4f acc[4][4];
#pragma unroll
    for (int i = 0; i < 4; ++i)
#pragma unroll
        for (int j = 0; j < 4; ++j) {
            v4f z = {0.f, 0.f, 0.f, 0.f};
            acc[i][j] = z;
        }

#pragma unroll
    for (int kc = 0; kc < 2; ++kc) {
        const ushort* Xsrc = kc ? aggxh : xh;
#pragma unroll
        for (int p = 0; p < 8; ++p) {
            int cid = p * 256 + tid;                 // 2048 chunks of 8 bf16
            int r = cid >> 4, c8 = cid & 15;
            int gr = rowBase + r;
            uint4 xv = make_uint4(0, 0, 0, 0);
            if (gr < M) xv = *(const uint4*)(Xsrc + (size_t)gr * 128 + c8 * 8);
            *(uint4*)(Xs + r * 128 + ((c8 ^ (r & 7)) << 3)) = xv;
            // W chunk: Wcat2[r][kc*128 + c8*8 ..], row stride 256
            uint4 wv4 = *(const uint4*)(Wcat2 + (size_t)r * 256 + kc * 128 + c8 * 8);
            *(uint4*)(Ws + r * 128 + ((c8 ^ (r & 7)) << 3)) = wv4;
        }
        __syncthreads();

#pragma unroll
        for (int ks = 0; ks < 4; ++ks) {
            const int chunk = ks * 4 + q;
            v8s a[4], b[4];
#pragma unroll
            for (int i = 0; i < 4; ++i) {
                int m = wrow + i * 16 + l16;
                a[i] = *(const v8s*)(Xs + m * 128 + ((chunk ^ (m & 7)) << 3));
            }
#pragma unroll
            for (int j = 0; j < 4; ++j) {
                int n = wcol + j * 16 + l16;
                b[j] = *(const v8s*)(Ws + n * 128 + ((chunk ^ (n & 7)) << 3));
            }
#pragma unroll
            for (int i = 0; i < 4; ++i)
#pragma unroll
                for (int j = 0; j < 4; ++j)
                    acc[i][j] = __builtin_amdgcn_mfma_f32_16x16x32_bf16(a[i], b[j], acc[i][j], 0, 0, 0);
        }
        __syncthreads();
    }

    // epilogue: x += eps*tanh(conv); xh = bf16(x)
#pragma unroll
    for (int j = 0; j < 4; ++j) {
        int col = wcol + j * 16 + l16;
        float bj = bconv[col];
#pragma unroll
        for (int i = 0; i < 4; ++i) {
            int grB = rowBase + wrow + i * 16 + q * 4;
#pragma unroll
            for (int r = 0; r < 4; ++r) {
                int gr = grB + r;
                if (gr < M) {
                    size_t off = (size_t)gr * 128 + col;
                    float conv = acc[i][j][r] + bj;
                    float xv = xF[off] + EPS_C * tanhf(conv);
                    xF[off] = xv;
                    xhOut[off] = f2bf(xv);
                }
            }
        }
    }
}

// ---------------------------------------------------------------------------
// CSR build (once per launch; edge structure is iteration-invariant)
// ---------------------------------------------------------------------------
__global__ __launch_bounds__(256) void zero_int_kernel(int* __restrict__ p, int n) {
    int i = blockIdx.x * 256 + threadIdx.x;
    if (i < n) p[i] = 0;
}

__global__ __launch_bounds__(256) void hist_kernel(const int* __restrict__ dst,
                                                   int* __restrict__ cnt) {
    int e = blockIdx.x * 256 + threadIdx.x;
    if (e < E_EDGES) atomicAdd(&cnt[dst[e]], 1);
}

// phase 1: per-block exclusive scan of deg -> localEx, block sums
__global__ __launch_bounds__(256) void scan_phase1(const int* __restrict__ deg,
                                                   int* __restrict__ localEx,
                                                   int* __restrict__ blockSums) {
    __shared__ int tmp[256];
    const int t = threadIdx.x;
    const int i = blockIdx.x * 256 + t;
    int v = (i < N_NODES) ? deg[i] : 0;
    tmp[t] = v;
    __syncthreads();
#pragma unroll
    for (int off = 1; off < 256; off <<= 1) {
        int u = (t >= off) ? tmp[t - off] : 0;
        __syncthreads();
        tmp[t] += u;
        __syncthreads();
    }
    if (i < N_NODES) localEx[i] = tmp[t] - v;
    if (t == 255) blockSums[blockIdx.x] = tmp[255];
}

// phase 2: single block scans the block sums -> exclusive offsets
__global__ __launch_bounds__(256) void scan_phase2(int* __restrict__ blockSums) {
    __shared__ int tmp[256];
    const int t = threadIdx.x;
    int v = (t < SCAN_BLOCKS) ? blockSums[t] : 0;
    tmp[t] = v;
    __syncthreads();
#pragma unroll
    for (int off = 1; off < 256; off <<= 1) {
        int u = (t >= off) ? tmp[t - off] : 0;
        __syncthreads();
        tmp[t] += u;
        __syncthreads();
    }
    if (t < SCAN_BLOCKS) blockSums[t] = tmp[t] - v;
}

// phase 3: add block offset; init cursor = rowStart
__global__ __launch_bounds__(256) void scan_phase3(int* __restrict__ rowStart,
                                                   const int* __restrict__ blockSums,
                                                   int* __restrict__ cursor) {
    const int i = blockIdx.x * 256 + threadIdx.x;
    if (i >= N_NODES) return;
    int v = rowStart[i] + blockSums[blockIdx.x];
    rowStart[i] = v;
    cursor[i] = v;
}

// scatter edges into CSR order, PACKED: es2[pos] = {src, bits(w)}
// (single 8B store/edge halves dirty-line amplification vs two 4B stores)
__global__ __launch_bounds__(256) void build_kernel(const int* __restrict__ src,
                                                    const int* __restrict__ dst,
                                                    const float* __restrict__ ew,
                                                    int* __restrict__ cursor,
                                                    int2* __restrict__ es2) {
    int e = blockIdx.x * 256 + threadIdx.x;
    if (e >= E_EDGES) return;
    int d = dst[e];
    int pos = atomicAdd(&cursor[d], 1);
    es2[pos] = make_int2(src[e], __float_as_int(ew[e]));
}

// ---------------------------------------------------------------------------
// Gather raw x (linearity: sum_e w*x[src] then one W_lin^T GEMM == reference).
// One 32-lane group per node, ushort4 (8B)/lane, unroll-4 for MLP.
// ---------------------------------------------------------------------------
__global__ __launch_bounds__(256) void gather_x_kernel(
        const ushort* __restrict__ xh, const int2* __restrict__ es2,
        const int* __restrict__ rowStart, const int* __restrict__ rowEnd,
        ushort* __restrict__ aggxh) {
    int gid = blockIdx.x * 256 + threadIdx.x;
    int node = gid >> 5;
    if (node >= N_NODES) return;
    int q = gid & 31;
    int e = rowStart[node], end = rowEnd[node];

    float4 s0 = make_float4(0.f, 0.f, 0.f, 0.f);
    float4 s1 = make_float4(0.f, 0.f, 0.f, 0.f);
    float4 s2 = make_float4(0.f, 0.f, 0.f, 0.f);
    float4 s3 = make_float4(0.f, 0.f, 0.f, 0.f);
    for (; e + 4 <= end; e += 4) {
        int2 m0 = es2[e], m1 = es2[e + 1], m2 = es2[e + 2], m3 = es2[e + 3];
        ushort4 v0 = *(const ushort4*)(xh + (size_t)m0.x * 128 + q * 4);
        ushort4 v1 = *(const ushort4*)(xh + (size_t)m1.x * 128 + q * 4);
        ushort4 v2 = *(const ushort4*)(xh + (size_t)m2.x * 128 + q * 4);
        ushort4 v3 = *(const ushort4*)(xh + (size_t)m3.x * 128 + q * 4);
        float w0 = __int_as_float(m0.y), w1 = __int_as_float(m1.y);
        float w2 = __int_as_float(m2.y), w3 = __int_as_float(m3.y);
        s0.x = fmaf(w0, bf2f(v0.x), s0.x); s0.y = fmaf(w0, bf2f(v0.y), s0.y);
        s0.z = fmaf(w0, bf2f(v0.z), s0.z); s0.w = fmaf(w0, bf2f(v0.w), s0.w);
        s1.x = fmaf(w1, bf2f(v1.x), s1.x); s1.y = fmaf(w1, bf2f(v1.y), s1.y);
        s1.z = fmaf(w1, bf2f(v1.z), s1.z); s1.w = fmaf(w1, bf2f(v1.w), s1.w);
        s2.x = fmaf(w2, bf2f(v2.x), s2.x); s2.y = fmaf(w2, bf2f(v2.y), s2.y);
        s2.z = fmaf(w2, bf2f(v2.z), s2.z); s2.w = fmaf(w2, bf2f(v2.w), s2.w);
        s3.x = fmaf(w3, bf2f(v3.x), s3.x); s3.y = fmaf(w3, bf2f(v3.y), s3.y);
        s3.z = fmaf(w3, bf2f(v3.z), s3.z); s3.w = fmaf(w3, bf2f(v3.w), s3.w);
    }
    for (; e < end; ++e) {
        int2 m = es2[e];
        float w = __int_as_float(m.y);
        ushort4 v = *(const ushort4*)(xh + (size_t)m.x * 128 + q * 4);
        s0.x = fmaf(w, bf2f(v.x), s0.x); s0.y = fmaf(w, bf2f(v.y), s0.y);
        s0.z = fmaf(w, bf2f(v.z), s0.z); s0.w = fmaf(w, bf2f(v.w), s0.w);
    }
    float4 sum = make_float4(s0.x + s1.x + s2.x + s3.x,
                             s0.y + s1.y + s2.y + s3.y,
                             s0.z + s1.z + s2.z + s3.z,
                             s0.w + s1.w + s2.w + s3.w);
    ushort4 h;
    h.x = f2bf(sum.x); h.y = f2bf(sum.y); h.z = f2bf(sum.z); h.w = f2bf(sum.w);
    *(ushort4*)(aggxh + (size_t)node * 128 + q * 4) = h;
}

// ---------------------------------------------------------------------------
// Readout: out = x @ W_out^T + b_out (fp32, swizzled LDS, conflict-free)
// ---------------------------------------------------------------------------
__global__ __launch_bounds__(256) void out_gemm(const float* __restrict__ X,
                                                const float* __restrict__ W,
                                                const float* __restrict__ bias,
                                                float* __restrict__ C, int M) {
    __shared__ float Xs[64 * 128];
    __shared__ float Ws[64 * 128];
    const int tid = threadIdx.x;
    const int rowBase = blockIdx.x * 64;

#pragma unroll
    for (int p = 0; p < 8; ++p) {
        int fi = p * 256 + tid;
        int r = fi >> 5, c4 = fi & 31;
        int gr = rowBase + r;
        float4 v = make_float4(0.f, 0.f, 0.f, 0.f);
        if (gr < M) v = *(const float4*)(X + (size_t)gr * 128 + c4 * 4);
        *(float4*)(Xs + r * 128 + ((c4 ^ ((r >> 2) & 7)) << 2)) = v;
    }
#pragma unroll
    for (int p = 0; p < 8; ++p) {
        int fi = p * 256 + tid;
        int r = fi >> 5, c4 = fi & 31;
        float4 v = make_float4(0.f, 0.f, 0.f, 0.f);
        if (r < OUT_DIM) v = *(const float4*)(W + (size_t)r * 128 + c4 * 4);
        *(float4*)(Ws + r * 128 + ((c4 ^ ((r >> 2) & 7)) << 2)) = v;
    }
    __syncthreads();

    const int tx = tid & 15, ty = tid >> 4;
    const int r0 = ty * 4, c0 = tx * 4;
    const int swx = ty & 7, swy = tx & 7;

    float acc[4][4] = {};
#pragma unroll 8
    for (int k4 = 0; k4 < 32; ++k4) {
        const int cox = (k4 ^ swx) << 2;
        const int cow = (k4 ^ swy) << 2;
        float4 a[4], b[4];
#pragma unroll
        for (int i = 0; i < 4; ++i) a[i] = *(const float4*)(Xs + (r0 + i) * 128 + cox);
#pragma unroll
        for (int j = 0; j < 4; ++j) b[j] = *(const float4*)(Ws + (c0 + j) * 128 + cow);
#pragma unroll
        for (int i = 0; i < 4; ++i)
#pragma unroll
            for (int j = 0; j < 4; ++j) {
                acc[i][j] = fmaf(a[i].x, b[j].x, acc[i][j]);
                acc[i][j] = fmaf(a[i].y, b[j].y, acc[i][j]);
                acc[i][j] = fmaf(a[i].z, b[j].z, acc[i][j]);
                acc[i][j] = fmaf(a[i].w, b[j].w, acc[i][j]);
            }
    }

    if (c0 < OUT_DIM) {
        float4 bv = *(const float4*)(bias + c0);
#pragma unroll
        for (int i = 0; i < 4; ++i) {
            int gr = rowBase + r0 + i;
            if (gr >= M) continue;
            float4 v = make_float4(acc[i][0] + bv.x, acc[i][1] + bv.y,
                                   acc[i][2] + bv.z, acc[i][3] + bv.w);
            *(float4*)(C + (size_t)gr * OUT_DIM + c0) = v;
        }
    }
}

extern "C" void kernel_launch(void* const* d_in, const int* in_sizes, int n_in,
                              void* d_out, int out_size, void* d_ws, size_t ws_size,
                              hipStream_t stream) {
    const float* x_in   = (const float*)d_in[0];
    const int*   ei     = (const int*)  d_in[1];   // (2,E) int32: src=ei, dst=ei+E
    const float* ew     = (const float*)d_in[2];
    const float* W_emb  = (const float*)d_in[3];
    const float* b_emb  = (const float*)d_in[4];
    const float* W_lin  = (const float*)d_in[5];
    const float* W_anti = (const float*)d_in[6];
    const float* b_conv = (const float*)d_in[7];
    const float* W_out  = (const float*)d_in[8];
    const float* b_out  = (const float*)d_in[9];
    float* out = (float*)d_out;

    // workspace: xF(f32) | xh(bf16) | aggxh(bf16) | WembH | Wcat2H |
    //            rowStart | cursor | es2(int2) | blockSums    (~57 MB)
    float*  xF     = (float*)d_ws;
    ushort* xh     = (ushort*)(xF + (size_t)N_NODES * D_DIM);
    ushort* aggxh  = xh + (size_t)N_NODES * D_DIM;
    ushort* WembH  = aggxh + (size_t)N_NODES * D_DIM;
    ushort* Wcat2H = WembH + D_DIM * D_DIM;
    int*    rowStart = (int*)(Wcat2H + 2 * D_DIM * D_DIM);
    int*    cursor   = rowStart + N_NODES;
    int2*   es2      = (int2*)(cursor + N_NODES);
    int*    blockSums = (int*)(es2 + E_EDGES);

    const int* src = ei;
    const int* dst = ei + E_EDGES;
    const int edgeBlocks = (E_EDGES + 255) / 256;
    const int gemmBlocksX = (N_NODES + 127) / 128;       // 391

    // ---- CSR build (once; structure is iteration-invariant) ----
    zero_int_kernel<<<SCAN_BLOCKS, 256, 0, stream>>>(cursor, N_NODES);
    hist_kernel<<<edgeBlocks, 256, 0, stream>>>(dst, cursor);
    scan_phase1<<<SCAN_BLOCKS, 256, 0, stream>>>(cursor, rowStart, blockSums);
    scan_phase2<<<1, 256, 0, stream>>>(blockSums);
    scan_phase3<<<SCAN_BLOCKS, 256, 0, stream>>>(rowStart, blockSums, cursor);
    build_kernel<<<edgeBlocks, 256, 0, stream>>>(src, dst, ew, cursor, es2);
    // after build: cursor[d] == row end offset

    // ---- weights to bf16 ----
    prep_w_kernel<<<64, 256, 0, stream>>>(W_emb, W_lin, W_anti, WembH, Wcat2H);

    // ---- embed ----
    mfma_embed_gemm<<<gemmBlocksX, 256, 0, stream>>>(x_in, WembH, b_emb, xF, xh, N_NODES);

    for (int it = 0; it < N_ITERS; ++it) {
        gather_x_kernel<<<(N_NODES * 32 + 255) / 256, 256, 0, stream>>>(
            xh, es2, rowStart, cursor, aggxh);
        mfma_conv_update<<<gemmBlocksX, 256, 0, stream>>>(
            xh, aggxh, Wcat2H, b_conv, xF, xh, N_NODES);
    }
    out_gemm<<<(N_NODES + 63) / 64, 256, 0, stream>>>(xF, W_out, b_out, out, N_NODES);
}